// Round 1
// baseline (24.247 us; speedup 1.0000x reference)
//
#include <hip/hip_runtime.h>

#define NF     26
#define CARD   100
#define EDIM   16
#define NDENSE 13
#define COLS   2626   // NF*(CARD+1)
#define NLOOK  2600   // NF*CARD
#define NTHR   256

__global__ __launch_bounds__(NTHR) void fm_kernel(
    const int*   __restrict__ sparse,   // B x 2626 (int32)
    const float* __restrict__ dense,    // B x 13
    const float* __restrict__ lin_t,    // 26*100
    const float* __restrict__ emb_t,    // 26*100*16
    const float* __restrict__ lw,       // 39
    const float* __restrict__ lb,       // 1
    float*       __restrict__ out)      // B
{
    __shared__ float s_lin[NLOOK];
    __shared__ float s_w[NF + NDENSE];
    __shared__ float red[4][EDIM + 2];

    const int b = blockIdx.x;
    const int t = threadIdx.x;

    // stage linear table + weights into LDS (coalesced)
    for (int i = t; i < NLOOK; i += NTHR) s_lin[i] = lin_t[i];
    if (t < NF + NDENSE) s_w[t] = lw[t];
    __syncthreads();

    const int* row = sparse + (size_t)b * COLS;

    float s[EDIM];
    #pragma unroll
    for (int e = 0; e < EDIM; ++e) s[e] = 0.f;
    float sos = 0.f;
    float lin = 0.f;

    for (int k = t; k < NLOOK; k += NTHR) {
        const int f   = k / CARD;        // magic-mul division
        const int col = k + f;           // f*101 + (k - f*100)
        const int idx = row[col];
        const float4* e4 = reinterpret_cast<const float4*>(
            emb_t + (size_t)(f * CARD + idx) * EDIM);
        const float4 a = e4[0];
        const float4 c = e4[1];
        const float4 d = e4[2];
        const float4 g = e4[3];

        s[0]  += a.x; s[1]  += a.y; s[2]  += a.z; s[3]  += a.w;
        s[4]  += c.x; s[5]  += c.y; s[6]  += c.z; s[7]  += c.w;
        s[8]  += d.x; s[9]  += d.y; s[10] += d.z; s[11] += d.w;
        s[12] += g.x; s[13] += g.y; s[14] += g.z; s[15] += g.w;

        sos += a.x*a.x + a.y*a.y + a.z*a.z + a.w*a.w
             + c.x*c.x + c.y*c.y + c.z*c.z + c.w*c.w
             + d.x*d.x + d.y*d.y + d.z*d.z + d.w*d.w
             + g.x*g.x + g.y*g.y + g.z*g.z + g.w*g.w;

        lin += s_lin[f * CARD + idx] * s_w[f];
    }

    // wave-level reduction (wave = 64 lanes on CDNA)
    #pragma unroll
    for (int off = 32; off > 0; off >>= 1) {
        #pragma unroll
        for (int e = 0; e < EDIM; ++e) s[e] += __shfl_down(s[e], off, 64);
        sos += __shfl_down(sos, off, 64);
        lin += __shfl_down(lin, off, 64);
    }

    const int wave = t >> 6;
    if ((t & 63) == 0) {
        #pragma unroll
        for (int e = 0; e < EDIM; ++e) red[wave][e] = s[e];
        red[wave][EDIM]     = sos;
        red[wave][EDIM + 1] = lin;
    }
    __syncthreads();

    if (t == 0) {
        float fs, fsos = 0.f, flin = 0.f, pair = 0.f;
        #pragma unroll
        for (int e = 0; e < EDIM; ++e) {
            fs = red[0][e] + red[1][e] + red[2][e] + red[3][e];
            pair += fs * fs;
        }
        fsos = red[0][EDIM] + red[1][EDIM] + red[2][EDIM] + red[3][EDIM];
        flin = red[0][EDIM+1] + red[1][EDIM+1] + red[2][EDIM+1] + red[3][EDIM+1];

        pair = 0.5f * (pair - fsos);

        float acc = flin + lb[0];
        const float* drow = dense + (size_t)b * NDENSE;
        #pragma unroll
        for (int dd = 0; dd < NDENSE; ++dd) acc += drow[dd] * s_w[NF + dd];

        out[b] = acc + pair;
    }
}

extern "C" void kernel_launch(void* const* d_in, const int* in_sizes, int n_in,
                              void* d_out, int out_size, void* d_ws, size_t ws_size,
                              hipStream_t stream) {
    const int*   sparse = (const int*)  d_in[0];
    const float* dense  = (const float*)d_in[1];
    const float* lin_t  = (const float*)d_in[2];
    const float* emb_t  = (const float*)d_in[3];
    const float* lw     = (const float*)d_in[4];
    const float* lb     = (const float*)d_in[5];
    float* out = (float*)d_out;

    const int B = out_size;  // 1024

    fm_kernel<<<B, NTHR, 0, stream>>>(sparse, dense, lin_t, emb_t, lw, lb, out);
}

// Round 4
// 21.936 us; speedup vs baseline: 1.1054x; 1.1054x over previous
//
#include <hip/hip_runtime.h>

#define NF     26
#define CARD   100
#define EDIM   16
#define NDENSE 13
#define COLS   2626   // NF*(CARD+1)
#define NLOOK  2600   // NF*CARD
#define NTHR   256
#define LPB    64     // lookups per block-iteration (NTHR/4)
#define NITER  41     // ceil(NLOOK/LPB)

__global__ __launch_bounds__(NTHR) void fm_kernel(
    const int*   __restrict__ sparse,   // B x 2626 (int32)
    const float* __restrict__ dense,    // B x 13
    const float* __restrict__ lin_t,    // 26*100
    const float* __restrict__ emb_t,    // 26*100*16
    const float* __restrict__ lw,       // 39
    const float* __restrict__ lb,       // 1
    float*       __restrict__ out)      // B
{
    __shared__ float s_lin[NLOOK];
    __shared__ float s_w[NF + NDENSE];
    __shared__ float red[4][EDIM + 2];

    const int b = blockIdx.x;
    const int t = threadIdx.x;

    // stage linear table (10.4 KB) + weights into LDS
    for (int i = t; i < NLOOK; i += NTHR) s_lin[i] = lin_t[i];
    if (t < NF + NDENSE) s_w[t] = lw[t];
    __syncthreads();

    const int* row = sparse + (size_t)b * COLS;

    const int q = t >> 2;   // lookup slot within block-iter
    const int c = t & 3;    // 16B chunk of the 64B embedding row

    float4 sq = make_float4(0.f, 0.f, 0.f, 0.f);
    float  sos = 0.f;
    float  lin = 0.f;

    #pragma unroll 4
    for (int i = 0; i < NITER; ++i) {
        const int k = q + i * LPB;
        if (k < NLOOK) {
            const int f     = k / CARD;       // magic-mul
            const int idx   = row[k + f];     // col = f*101 + (k - f*100)
            const int rowid = f * CARD + idx;
            const float4 v  = *reinterpret_cast<const float4*>(
                emb_t + (rowid << 4) + (c << 2));
            sq.x += v.x; sq.y += v.y; sq.z += v.z; sq.w += v.w;
            sos  += v.x * v.x + v.y * v.y + v.z * v.z + v.w * v.w;
            lin  += s_lin[rowid] * s_w[f];    // 4x redundant per quad; scaled later
        }
    }

    // wave reduce: chunk-preserving for sq (stop at offset 4), full for sos/lin
    #pragma unroll
    for (int off = 32; off >= 4; off >>= 1) {
        sq.x += __shfl_down(sq.x, off, 64);
        sq.y += __shfl_down(sq.y, off, 64);
        sq.z += __shfl_down(sq.z, off, 64);
        sq.w += __shfl_down(sq.w, off, 64);
        sos  += __shfl_down(sos,  off, 64);
        lin  += __shfl_down(lin,  off, 64);
    }
    sos += __shfl_down(sos, 2, 64);  lin += __shfl_down(lin, 2, 64);
    sos += __shfl_down(sos, 1, 64);  lin += __shfl_down(lin, 1, 64);

    const int wave = t >> 6;
    const int lane = t & 63;
    if (lane < 4) {   // lane L holds chunk L sums (elements 4L..4L+3)
        red[wave][lane * 4 + 0] = sq.x;
        red[wave][lane * 4 + 1] = sq.y;
        red[wave][lane * 4 + 2] = sq.z;
        red[wave][lane * 4 + 3] = sq.w;
    }
    if (lane == 0) {
        red[wave][EDIM]     = sos;
        red[wave][EDIM + 1] = lin;
    }
    __syncthreads();

    if (t == 0) {
        float pair = 0.f;
        #pragma unroll
        for (int e = 0; e < EDIM; ++e) {
            const float fs = red[0][e] + red[1][e] + red[2][e] + red[3][e];
            pair += fs * fs;
        }
        const float fsos = red[0][EDIM] + red[1][EDIM] + red[2][EDIM] + red[3][EDIM];
        const float flin = 0.25f * (red[0][EDIM+1] + red[1][EDIM+1] +
                                    red[2][EDIM+1] + red[3][EDIM+1]);

        pair = 0.5f * (pair - fsos);

        float acc = flin + lb[0];
        const float* drow = dense + (size_t)b * NDENSE;
        #pragma unroll
        for (int dd = 0; dd < NDENSE; ++dd) acc += drow[dd] * s_w[NF + dd];

        out[b] = acc + pair;
    }
}

extern "C" void kernel_launch(void* const* d_in, const int* in_sizes, int n_in,
                              void* d_out, int out_size, void* d_ws, size_t ws_size,
                              hipStream_t stream) {
    const int*   sparse = (const int*)  d_in[0];
    const float* dense  = (const float*)d_in[1];
    const float* lin_t  = (const float*)d_in[2];
    const float* emb_t  = (const float*)d_in[3];
    const float* lw     = (const float*)d_in[4];
    const float* lb     = (const float*)d_in[5];
    float* out = (float*)d_out;

    const int B = out_size;  // 1024

    fm_kernel<<<B, NTHR, 0, stream>>>(sparse, dense, lin_t, emb_t, lw, lb, out);
}

// Round 8
// 15.660 us; speedup vs baseline: 1.5483x; 1.4007x over previous
//
#include <hip/hip_runtime.h>

#define NF     26
#define CARD   100
#define EDIM   16
#define NDENSE 13
#define COLS   2626   // NF*(CARD+1)
#define NLOOK  2600   // NF*CARD
#define NT     512
#define G      2      // batch rows per block
#define NQUAD  128    // NT/4
#define MAIN_ITERS 20 // 2600 = 128*20 + 40
#define TAIL_QUADS 40

__global__ __launch_bounds__(NT) void fm_kernel(
    const int*   __restrict__ sparse,   // B x 2626 (int32)
    const float* __restrict__ dense,    // B x 13
    const float* __restrict__ lin_t,    // 2600
    const float* __restrict__ emb_t,    // 2600 x 16
    const float* __restrict__ lw,       // 39
    const float* __restrict__ lb,       // 1
    float*       __restrict__ out)      // B
{
    __shared__ unsigned cnt[G * NLOOK];     // 20.8 KB
    __shared__ float    s_w[NF + NDENSE];
    __shared__ float    red[8][G][EDIM + 2];

    const int blk = blockIdx.x;
    const int t   = threadIdx.x;

    // ---- phase 0: zero counts, stage weights ----
    for (int i = t; i < G * NLOOK; i += NT) cnt[i] = 0u;
    if (t < NF + NDENSE) s_w[t] = lw[t];
    __syncthreads();

    // ---- phase 1: build count vectors (scattered LDS atomics, cheap) ----
    #pragma unroll
    for (int g = 0; g < G; ++g) {
        const int* row = sparse + (size_t)(G * blk + g) * COLS;
        for (int i = t; i < NLOOK; i += NT) {
            const int f   = i / CARD;            // const-div -> magic mul
            const int idx = row[i + f];          // col = f*101 + (i - f*100)
            atomicAdd(&cnt[g * NLOOK + f * CARD + idx], 1u);
        }
    }
    __syncthreads();

    // ---- phase 2: dense stream of the table, weighted by counts ----
    const int quad = t >> 2;   // 0..127
    const int c    = t & 3;    // 16B chunk of the 64B embedding row

    float4 s0 = make_float4(0.f, 0.f, 0.f, 0.f);
    float4 s1 = make_float4(0.f, 0.f, 0.f, 0.f);
    float sos0 = 0.f, sos1 = 0.f, lin0 = 0.f, lin1 = 0.f;

    #pragma unroll 5
    for (int i = 0; i < MAIN_ITERS; ++i) {
        const int r = quad + i * NQUAD;
        const float4 v = *reinterpret_cast<const float4*>(emb_t + (r << 4) + (c << 2));
        const float lt  = lin_t[r];
        const int   f   = r / CARD;
        const float lv  = lt * s_w[f];
        const float fc0 = (float)cnt[r];
        const float fc1 = (float)cnt[NLOOK + r];
        const float ssq = v.x*v.x + v.y*v.y + v.z*v.z + v.w*v.w;
        s0.x += fc0 * v.x; s0.y += fc0 * v.y; s0.z += fc0 * v.z; s0.w += fc0 * v.w;
        s1.x += fc1 * v.x; s1.y += fc1 * v.y; s1.z += fc1 * v.z; s1.w += fc1 * v.w;
        sos0 += fc0 * ssq; sos1 += fc1 * ssq;
        lin0 += fc0 * lv;  lin1 += fc1 * lv;   // 4x redundant per quad; scaled later
    }
    if (quad < TAIL_QUADS) {                   // rows 2560..2599
        const int r = quad + MAIN_ITERS * NQUAD;
        const float4 v = *reinterpret_cast<const float4*>(emb_t + (r << 4) + (c << 2));
        const float lt  = lin_t[r];
        const int   f   = r / CARD;
        const float lv  = lt * s_w[f];
        const float fc0 = (float)cnt[r];
        const float fc1 = (float)cnt[NLOOK + r];
        const float ssq = v.x*v.x + v.y*v.y + v.z*v.z + v.w*v.w;
        s0.x += fc0 * v.x; s0.y += fc0 * v.y; s0.z += fc0 * v.z; s0.w += fc0 * v.w;
        s1.x += fc1 * v.x; s1.y += fc1 * v.y; s1.z += fc1 * v.z; s1.w += fc1 * v.w;
        sos0 += fc0 * ssq; sos1 += fc1 * ssq;
        lin0 += fc0 * lv;  lin1 += fc1 * lv;
    }

    // ---- phase 3: reduction (wave = 64 lanes) ----
    #pragma unroll
    for (int off = 32; off >= 4; off >>= 1) {
        s0.x += __shfl_down(s0.x, off, 64); s0.y += __shfl_down(s0.y, off, 64);
        s0.z += __shfl_down(s0.z, off, 64); s0.w += __shfl_down(s0.w, off, 64);
        s1.x += __shfl_down(s1.x, off, 64); s1.y += __shfl_down(s1.y, off, 64);
        s1.z += __shfl_down(s1.z, off, 64); s1.w += __shfl_down(s1.w, off, 64);
        sos0 += __shfl_down(sos0, off, 64); sos1 += __shfl_down(sos1, off, 64);
        lin0 += __shfl_down(lin0, off, 64); lin1 += __shfl_down(lin1, off, 64);
    }
    sos0 += __shfl_down(sos0, 2, 64); sos1 += __shfl_down(sos1, 2, 64);
    lin0 += __shfl_down(lin0, 2, 64); lin1 += __shfl_down(lin1, 2, 64);
    sos0 += __shfl_down(sos0, 1, 64); sos1 += __shfl_down(sos1, 1, 64);
    lin0 += __shfl_down(lin0, 1, 64); lin1 += __shfl_down(lin1, 1, 64);

    const int wave = t >> 6;   // 0..7
    const int lane = t & 63;
    if (lane < 4) {            // lane L holds chunk L (elements 4L..4L+3)
        red[wave][0][lane*4+0] = s0.x; red[wave][0][lane*4+1] = s0.y;
        red[wave][0][lane*4+2] = s0.z; red[wave][0][lane*4+3] = s0.w;
        red[wave][1][lane*4+0] = s1.x; red[wave][1][lane*4+1] = s1.y;
        red[wave][1][lane*4+2] = s1.z; red[wave][1][lane*4+3] = s1.w;
    }
    if (lane == 0) {
        red[wave][0][EDIM] = sos0; red[wave][0][EDIM+1] = lin0;
        red[wave][1][EDIM] = sos1; red[wave][1][EDIM+1] = lin1;
    }
    __syncthreads();

    if (t < G) {
        const int g = t;
        float pair = 0.f;
        #pragma unroll
        for (int e = 0; e < EDIM; ++e) {
            float fs = 0.f;
            #pragma unroll
            for (int w = 0; w < 8; ++w) fs += red[w][g][e];
            pair += fs * fs;
        }
        float fsos = 0.f, flin = 0.f;
        #pragma unroll
        for (int w = 0; w < 8; ++w) { fsos += red[w][g][EDIM]; flin += red[w][g][EDIM+1]; }
        flin *= 0.25f;                       // quad redundancy
        pair = 0.5f * (pair - fsos);

        const int b = G * blk + g;
        float acc = flin + lb[0];
        const float* drow = dense + (size_t)b * NDENSE;
        #pragma unroll
        for (int dd = 0; dd < NDENSE; ++dd) acc += drow[dd] * s_w[NF + dd];

        out[b] = acc + pair;
    }
}

extern "C" void kernel_launch(void* const* d_in, const int* in_sizes, int n_in,
                              void* d_out, int out_size, void* d_ws, size_t ws_size,
                              hipStream_t stream) {
    const int*   sparse = (const int*)  d_in[0];
    const float* dense  = (const float*)d_in[1];
    const float* lin_t  = (const float*)d_in[2];
    const float* emb_t  = (const float*)d_in[3];
    const float* lw     = (const float*)d_in[4];
    const float* lb     = (const float*)d_in[5];
    float* out = (float*)d_out;

    const int B = out_size;  // 1024
    fm_kernel<<<B / G, NT, 0, stream>>>(sparse, dense, lin_t, emb_t, lw, lb, out);
}